// Round 1
// baseline (292.154 us; speedup 1.0000x reference)
//
#include <hip/hip_runtime.h>
#include <hip/hip_bf16.h>
#include <math.h>

#define TT 3
#define HH 96
#define WWD 96
#define CCH 128
#define NHD 8
#define DHD 16
#define NP 25
#define NROWS (TT*HH*WWD)   // 27648

// ---------------- Kernel 1: fused QKV projection + bias epilogue ----------------
// grid = NROWS/32 = 864 blocks, 256 threads. Each block: 32 rows x 128 cols x 3 mats.
__launch_bounds__(256)
__global__ void qkv_kernel(const float* __restrict__ x,
                           const float* __restrict__ Wq,
                           const float* __restrict__ Wk,
                           const float* __restrict__ Wv,
                           const float* __restrict__ temp_emb,
                           const float* __restrict__ sp_emb,
                           float* __restrict__ Qb,
                           float* __restrict__ Kb,
                           float* __restrict__ Vb) {
    __shared__ __align__(16) float xs[32][132];
    __shared__ __align__(16) float ws[64][132];
    const int tid = threadIdx.x;
    const int tx = tid & 31;        // col group: cols tx*4..tx*4+3
    const int ty = tid >> 5;        // row group: rows ty*4..ty*4+3
    const int r0 = blockIdx.x * 32;

    // load x tile: 32 rows x 128 (contiguous 16 KB)
    {
        const float4* src = (const float4*)(x + (size_t)r0 * CCH);
        for (int e = tid; e < 32 * 128 / 4; e += 256) {
            float4 v4 = src[e];
            int r = (e * 4) >> 7;
            int c = (e * 4) & 127;
            *(float4*)&xs[r][c] = v4;
        }
    }

    const float* Ws[3] = {Wq, Wk, Wv};
    float* Outs[3] = {Qb, Kb, Vb};

    for (int m = 0; m < 3; ++m) {
        float acc[4][4];
#pragma unroll
        for (int i = 0; i < 4; ++i)
#pragma unroll
            for (int j = 0; j < 4; ++j) acc[i][j] = 0.f;
        const float* Wm = Ws[m];
        for (int c0 = 0; c0 < 128; c0 += 64) {
            __syncthreads();   // guard xs load (first iter) / previous chunk compute
            const float4* wsrc = (const float4*)(Wm + (size_t)c0 * CCH);
            for (int e = tid; e < 64 * 128 / 4; e += 256) {
                float4 v4 = wsrc[e];
                int r = (e * 4) >> 7;
                int c = (e * 4) & 127;
                *(float4*)&ws[r][c] = v4;
            }
            __syncthreads();
#pragma unroll 8
            for (int cc = 0; cc < 64; ++cc) {
                float4 w4 = *(const float4*)&ws[cc][tx * 4];
#pragma unroll
                for (int i = 0; i < 4; ++i) {
                    float xv = xs[ty * 4 + i][c0 + cc];
                    acc[i][0] += xv * w4.x;
                    acc[i][1] += xv * w4.y;
                    acc[i][2] += xv * w4.z;
                    acc[i][3] += xv * w4.w;
                }
            }
        }
        // epilogue: bias + store
#pragma unroll
        for (int i = 0; i < 4; ++i) {
            int row = r0 + ty * 4 + i;
            int t = row / (HH * WWD);
            int rem = row - t * (HH * WWD);
            int yy = rem / WWD;
            int xx = rem - yy * WWD;
            int k0 = tx * 4;
            float4 o;
            o.x = acc[i][0]; o.y = acc[i][1]; o.z = acc[i][2]; o.w = acc[i][3];
            if (m == 0) {
                int yr = yy - min(max(yy, 2), 93) + 2;
                int xr = xx - min(max(xx, 2), 93) + 2;
                int qidx = yr * 5 + xr;
                o.x += temp_emb[t * CCH + k0 + 0] + sp_emb[qidx * CCH + k0 + 0];
                o.y += temp_emb[t * CCH + k0 + 1] + sp_emb[qidx * CCH + k0 + 1];
                o.z += temp_emb[t * CCH + k0 + 2] + sp_emb[qidx * CCH + k0 + 2];
                o.w += temp_emb[t * CCH + k0 + 3] + sp_emb[qidx * CCH + k0 + 3];
            } else if (m == 1) {
                o.x += temp_emb[t * CCH + k0 + 0];
                o.y += temp_emb[t * CCH + k0 + 1];
                o.z += temp_emb[t * CCH + k0 + 2];
                o.w += temp_emb[t * CCH + k0 + 3];
            }
            *(float4*)&Outs[m][(size_t)row * CCH + k0] = o;
        }
    }
}

// ---------------- Kernel 2: local attention, one thread per (query, head) ----------------
// 27648 queries * 8 heads = 221184 threads = 864 blocks x 256.
// Writes attention output in place over Qb (each thread owns a disjoint 16-float slice).
__launch_bounds__(256)
__global__ void attn_kernel(const float* Qb,
                            const float* __restrict__ Kb,
                            const float* __restrict__ Vb,
                            const float* __restrict__ sp_emb,
                            float* Ob) {
    __shared__ __align__(16) float sp[NP * CCH];   // 12.8 KB
    for (int e = threadIdx.x; e < NP * CCH; e += 256) sp[e] = sp_emb[e];
    __syncthreads();

    int g = blockIdx.x * 256 + threadIdx.x;
    int q = g >> 3;
    int h = g & 7;
    int rem = q % (HH * WWD);
    int yy = rem / WWD;
    int xx = rem - yy * WWD;
    int yc = min(max(yy, 2), 93);
    int xc = min(max(xx, 2), 93);
    int h16 = h * 16;

    float qv[16];
#pragma unroll
    for (int d4 = 0; d4 < 4; ++d4) {
        float4 v4 = *(const float4*)&Qb[(size_t)q * CCH + h16 + d4 * 4];
        qv[d4 * 4 + 0] = v4.x; qv[d4 * 4 + 1] = v4.y;
        qv[d4 * 4 + 2] = v4.z; qv[d4 * 4 + 3] = v4.w;
    }

    float mr = -1e30f, l = 0.f;
    float acc[16];
#pragma unroll
    for (int d = 0; d < 16; ++d) acc[d] = 0.f;

    for (int tk = 0; tk < TT; ++tk) {
        for (int py = 0; py < 5; ++py) {
            int yn = yc + py - 2;
#pragma unroll
            for (int px = 0; px < 5; ++px) {
                int xn = xc + px - 2;
                int p = py * 5 + px;
                size_t koff = ((size_t)(tk * HH + yn) * WWD + xn) * CCH + h16;
                const float* kp = Kb + koff;
                const float* spp = sp + p * CCH + h16;
                float s = 0.f;
#pragma unroll
                for (int d4 = 0; d4 < 4; ++d4) {
                    float4 k4 = *(const float4*)(kp + d4 * 4);
                    float4 s4 = *(const float4*)(spp + d4 * 4);
                    s += qv[d4 * 4 + 0] * (k4.x + s4.x) + qv[d4 * 4 + 1] * (k4.y + s4.y)
                       + qv[d4 * 4 + 2] * (k4.z + s4.z) + qv[d4 * 4 + 3] * (k4.w + s4.w);
                }
                s *= 0.25f;
                float mn = fmaxf(mr, s);
                float corr = __expf(mr - mn);
                float w = __expf(s - mn);
                l = l * corr + w;
                mr = mn;
                const float* vp = Vb + koff;
#pragma unroll
                for (int d4 = 0; d4 < 4; ++d4) {
                    float4 v4 = *(const float4*)(vp + d4 * 4);
                    acc[d4 * 4 + 0] = acc[d4 * 4 + 0] * corr + w * v4.x;
                    acc[d4 * 4 + 1] = acc[d4 * 4 + 1] * corr + w * v4.y;
                    acc[d4 * 4 + 2] = acc[d4 * 4 + 2] * corr + w * v4.z;
                    acc[d4 * 4 + 3] = acc[d4 * 4 + 3] * corr + w * v4.w;
                }
            }
        }
    }
    float inv = 1.f / l;
#pragma unroll
    for (int d4 = 0; d4 < 4; ++d4) {
        float4 o;
        o.x = acc[d4 * 4 + 0] * inv;
        o.y = acc[d4 * 4 + 1] * inv;
        o.z = acc[d4 * 4 + 2] * inv;
        o.w = acc[d4 * 4 + 3] * inv;
        *(float4*)&Ob[(size_t)q * CCH + h16 + d4 * 4] = o;
    }
}

// ---------------- Kernel 3: output projection + (y,x,t) transpose scatter ----------------
__launch_bounds__(256)
__global__ void out_proj_kernel(const float* __restrict__ A,   // attn out [NROWS][128]
                                const float* __restrict__ Wo,
                                float* __restrict__ out) {
    __shared__ __align__(16) float xs[32][132];
    __shared__ __align__(16) float ws[64][132];
    const int tid = threadIdx.x;
    const int tx = tid & 31;
    const int ty = tid >> 5;
    const int r0 = blockIdx.x * 32;

    {
        const float4* src = (const float4*)(A + (size_t)r0 * CCH);
        for (int e = tid; e < 32 * 128 / 4; e += 256) {
            float4 v4 = src[e];
            int r = (e * 4) >> 7;
            int c = (e * 4) & 127;
            *(float4*)&xs[r][c] = v4;
        }
    }

    float acc[4][4];
#pragma unroll
    for (int i = 0; i < 4; ++i)
#pragma unroll
        for (int j = 0; j < 4; ++j) acc[i][j] = 0.f;

    for (int c0 = 0; c0 < 128; c0 += 64) {
        __syncthreads();
        const float4* wsrc = (const float4*)(Wo + (size_t)c0 * CCH);
        for (int e = tid; e < 64 * 128 / 4; e += 256) {
            float4 v4 = wsrc[e];
            int r = (e * 4) >> 7;
            int c = (e * 4) & 127;
            *(float4*)&ws[r][c] = v4;
        }
        __syncthreads();
#pragma unroll 8
        for (int cc = 0; cc < 64; ++cc) {
            float4 w4 = *(const float4*)&ws[cc][tx * 4];
#pragma unroll
            for (int i = 0; i < 4; ++i) {
                float xv = xs[ty * 4 + i][c0 + cc];
                acc[i][0] += xv * w4.x;
                acc[i][1] += xv * w4.y;
                acc[i][2] += xv * w4.z;
                acc[i][3] += xv * w4.w;
            }
        }
    }
#pragma unroll
    for (int i = 0; i < 4; ++i) {
        int row = r0 + ty * 4 + i;
        int t = row / (HH * WWD);
        int rem = row - t * (HH * WWD);
        int yy = rem / WWD;
        int xx = rem - yy * WWD;
        int k0 = tx * 4;
        float4 o;
        o.x = acc[i][0]; o.y = acc[i][1]; o.z = acc[i][2]; o.w = acc[i][3];
        size_t oidx = ((size_t)(yy * WWD + xx) * TT + t) * CCH + k0;
        *(float4*)&out[oidx] = o;
    }
}

extern "C" void kernel_launch(void* const* d_in, const int* in_sizes, int n_in,
                              void* d_out, int out_size, void* d_ws, size_t ws_size,
                              hipStream_t stream) {
    const float* x        = (const float*)d_in[0];
    const float* Wq       = (const float*)d_in[1];
    const float* Wk       = (const float*)d_in[2];
    const float* Wv       = (const float*)d_in[3];
    const float* Wo       = (const float*)d_in[4];
    const float* temp_emb = (const float*)d_in[5];
    const float* sp_emb   = (const float*)d_in[6];
    float* out = (float*)d_out;

    float* Qb = (float*)d_ws;
    float* Kb = Qb + (size_t)NROWS * CCH;
    float* Vb = Kb + (size_t)NROWS * CCH;

    qkv_kernel<<<NROWS / 32, 256, 0, stream>>>(x, Wq, Wk, Wv, temp_emb, sp_emb, Qb, Kb, Vb);
    attn_kernel<<<NROWS * NHD / 256, 256, 0, stream>>>(Qb, Kb, Vb, sp_emb, Qb);
    out_proj_kernel<<<NROWS / 32, 256, 0, stream>>>(Qb, Wo, out);
}

// Round 2
// 229.010 us; speedup vs baseline: 1.2757x; 1.2757x over previous
//
#include <hip/hip_runtime.h>
#include <hip/hip_bf16.h>
#include <math.h>

#define TT 3
#define HH 96
#define WWD 96
#define CCH 128
#define NHD 8
#define DHD 16
#define NP 25
#define NROWS (TT*HH*WWD)   // 27648

// attention tile config
#define TY 4
#define TX 4
#define HY 8            // TY + 4 halo
#define HX 8            // TX + 4 halo
#define LSTR 132        // padded row stride (floats): 132 mod 32 = 4 -> balanced banks

// ---------------- Kernel 1: fused QKV projection + bias epilogue ----------------
__launch_bounds__(256)
__global__ void qkv_kernel(const float* __restrict__ x,
                           const float* __restrict__ Wq,
                           const float* __restrict__ Wk,
                           const float* __restrict__ Wv,
                           const float* __restrict__ temp_emb,
                           const float* __restrict__ sp_emb,
                           float* __restrict__ Qb,
                           float* __restrict__ Kb,
                           float* __restrict__ Vb) {
    __shared__ __align__(16) float xs[32][132];
    __shared__ __align__(16) float ws[64][132];
    const int tid = threadIdx.x;
    const int tx = tid & 31;
    const int ty = tid >> 5;
    const int r0 = blockIdx.x * 32;

    {
        const float4* src = (const float4*)(x + (size_t)r0 * CCH);
        for (int e = tid; e < 32 * 128 / 4; e += 256) {
            float4 v4 = src[e];
            int r = (e * 4) >> 7;
            int c = (e * 4) & 127;
            *(float4*)&xs[r][c] = v4;
        }
    }

    const float* Ws[3] = {Wq, Wk, Wv};
    float* Outs[3] = {Qb, Kb, Vb};

    for (int m = 0; m < 3; ++m) {
        float acc[4][4];
#pragma unroll
        for (int i = 0; i < 4; ++i)
#pragma unroll
            for (int j = 0; j < 4; ++j) acc[i][j] = 0.f;
        const float* Wm = Ws[m];
        for (int c0 = 0; c0 < 128; c0 += 64) {
            __syncthreads();
            const float4* wsrc = (const float4*)(Wm + (size_t)c0 * CCH);
            for (int e = tid; e < 64 * 128 / 4; e += 256) {
                float4 v4 = wsrc[e];
                int r = (e * 4) >> 7;
                int c = (e * 4) & 127;
                *(float4*)&ws[r][c] = v4;
            }
            __syncthreads();
#pragma unroll 8
            for (int cc = 0; cc < 64; ++cc) {
                float4 w4 = *(const float4*)&ws[cc][tx * 4];
#pragma unroll
                for (int i = 0; i < 4; ++i) {
                    float xv = xs[ty * 4 + i][c0 + cc];
                    acc[i][0] += xv * w4.x;
                    acc[i][1] += xv * w4.y;
                    acc[i][2] += xv * w4.z;
                    acc[i][3] += xv * w4.w;
                }
            }
        }
#pragma unroll
        for (int i = 0; i < 4; ++i) {
            int row = r0 + ty * 4 + i;
            int t = row / (HH * WWD);
            int rem = row - t * (HH * WWD);
            int yy = rem / WWD;
            int xx = rem - yy * WWD;
            int k0 = tx * 4;
            float4 o;
            o.x = acc[i][0]; o.y = acc[i][1]; o.z = acc[i][2]; o.w = acc[i][3];
            if (m == 0) {
                int yr = yy - min(max(yy, 2), 93) + 2;
                int xr = xx - min(max(xx, 2), 93) + 2;
                int qidx = yr * 5 + xr;
                o.x += temp_emb[t * CCH + k0 + 0] + sp_emb[qidx * CCH + k0 + 0];
                o.y += temp_emb[t * CCH + k0 + 1] + sp_emb[qidx * CCH + k0 + 1];
                o.z += temp_emb[t * CCH + k0 + 2] + sp_emb[qidx * CCH + k0 + 2];
                o.w += temp_emb[t * CCH + k0 + 3] + sp_emb[qidx * CCH + k0 + 3];
            } else if (m == 1) {
                o.x += temp_emb[t * CCH + k0 + 0];
                o.y += temp_emb[t * CCH + k0 + 1];
                o.z += temp_emb[t * CCH + k0 + 2];
                o.w += temp_emb[t * CCH + k0 + 3];
            }
            *(float4*)&Outs[m][(size_t)row * CCH + k0] = o;
        }
    }
}

// ---------------- Kernel 2: LDS-tiled local attention ----------------
// Block = 4x4 spatial query tile. 384 threads = 3 t_q x 16 q_local x 8 heads.
// Per key-frame: stage 8x8x128 K and V halo into LDS (stride 132), then each
// thread scores its 25 keys from LDS (batched softmax, one rescale/frame).
// Writes attention output in place over Qb (disjoint 16-float slices).
__launch_bounds__(384, 3)
__global__ void attn_kernel(const float* Qb,
                            const float* __restrict__ Kb,
                            const float* __restrict__ Vb,
                            const float* __restrict__ sp_emb,
                            float* Ob) {
    __shared__ __align__(16) float Ks[HY * HX * LSTR];
    __shared__ __align__(16) float Vs[HY * HX * LSTR];

    const int tid = threadIdx.x;
    const int h = tid & 7;
    const int ql = (tid >> 3) & 15;
    const int tq = tid >> 7;            // query frame 0..2
    const int qx = ql & 3;
    const int qy = ql >> 2;

    const int bx = blockIdx.x % (WWD / TX);
    const int by = blockIdx.x / (WWD / TX);
    const int x0 = bx * TX, y0 = by * TY;
    int xlo = min(max(x0, 2), 93) - 2; xlo = min(xlo, WWD - HX);
    int ylo = min(max(y0, 2), 93) - 2; ylo = min(ylo, HH - HY);

    const int yy = y0 + qy, xx = x0 + qx;
    const int yc = min(max(yy, 2), 93), xc = min(max(xx, 2), 93);
    const int lyo = yc - 2 - ylo;       // LDS y offset for py=0
    const int lxo = xc - 2 - xlo;
    const int h16 = h * DHD;
    const int qrow = tq * (HH * WWD) + yy * WWD + xx;

    // load Q (pre-scaled by 1/sqrt(d))
    float qv[16];
#pragma unroll
    for (int d4 = 0; d4 < 4; ++d4) {
        float4 v4 = *(const float4*)&Qb[(size_t)qrow * CCH + h16 + d4 * 4];
        qv[d4 * 4 + 0] = v4.x * 0.25f; qv[d4 * 4 + 1] = v4.y * 0.25f;
        qv[d4 * 4 + 2] = v4.z * 0.25f; qv[d4 * 4 + 3] = v4.w * 0.25f;
    }

    // precompute qsp[p] = qv_scaled . sp_emb[p] (score = qv.k + qsp[p])
    float qsp[NP];
#pragma unroll
    for (int p = 0; p < NP; ++p) {
        const float* spp = sp_emb + p * CCH + h16;
        float a0 = 0.f, a1 = 0.f, a2 = 0.f, a3 = 0.f;
#pragma unroll
        for (int d4 = 0; d4 < 4; ++d4) {
            float4 s4 = *(const float4*)(spp + d4 * 4);
            float d0 = qv[d4 * 4 + 0] * s4.x + qv[d4 * 4 + 1] * s4.y;
            float d1 = qv[d4 * 4 + 2] * s4.z + qv[d4 * 4 + 3] * s4.w;
            if (d4 == 0) { a0 = d0 + d1; } else if (d4 == 1) { a1 = d0 + d1; }
            else if (d4 == 2) { a2 = d0 + d1; } else { a3 = d0 + d1; }
        }
        qsp[p] = (a0 + a1) + (a2 + a3);
    }

    float m = -1e30f, l = 0.f;
    float acc[16];
#pragma unroll
    for (int d = 0; d < 16; ++d) acc[d] = 0.f;

    for (int t = 0; t < TT; ++t) {
        __syncthreads();   // protect LDS from previous frame's readers
        // stage K/V halo: 64 rows x 128 floats each
        {
            const size_t gbase = ((size_t)(t * HH + ylo) * WWD) * CCH;
            for (int e = tid; e < HY * HX * 32; e += 384) {
                int r = e >> 5;
                int c4 = (e & 31) * 4;
                int gy = r >> 3, gx = r & 7;
                size_t ga = gbase + ((size_t)gy * WWD + (xlo + gx)) * CCH + c4;
                int la = r * LSTR + c4;
                *(float4*)&Ks[la] = *(const float4*)&Kb[ga];
                *(float4*)&Vs[la] = *(const float4*)&Vb[ga];
            }
        }
        __syncthreads();

        // scores for 25 keys
        float s[NP];
#pragma unroll
        for (int py = 0; py < 5; ++py) {
            int rbase = (lyo + py) * HX + lxo;
#pragma unroll
            for (int px = 0; px < 5; ++px) {
                const float* kp = &Ks[(rbase + px) * LSTR + h16];
                float4 k0 = *(const float4*)(kp + 0);
                float4 k1 = *(const float4*)(kp + 4);
                float4 k2 = *(const float4*)(kp + 8);
                float4 k3 = *(const float4*)(kp + 12);
                float a0 = (qv[0] * k0.x + qv[1] * k0.y) + (qv[2] * k0.z + qv[3] * k0.w);
                float a1 = (qv[4] * k1.x + qv[5] * k1.y) + (qv[6] * k1.z + qv[7] * k1.w);
                float a2 = (qv[8] * k2.x + qv[9] * k2.y) + (qv[10] * k2.z + qv[11] * k2.w);
                float a3 = (qv[12] * k3.x + qv[13] * k3.y) + (qv[14] * k3.z + qv[15] * k3.w);
                s[py * 5 + px] = qsp[py * 5 + px] + ((a0 + a1) + (a2 + a3));
            }
        }

        // batched online softmax: one rescale per frame
        float fm = m;
#pragma unroll
        for (int p = 0; p < NP; ++p) fm = fmaxf(fm, s[p]);
        float corr = __expf(m - fm);
        m = fm;
        l *= corr;
#pragma unroll
        for (int d = 0; d < 16; ++d) acc[d] *= corr;
#pragma unroll
        for (int py = 0; py < 5; ++py) {
            int rbase = (lyo + py) * HX + lxo;
#pragma unroll
            for (int px = 0; px < 5; ++px) {
                float w = __expf(s[py * 5 + px] - fm);
                l += w;
                const float* vp = &Vs[(rbase + px) * LSTR + h16];
#pragma unroll
                for (int d4 = 0; d4 < 4; ++d4) {
                    float4 v4 = *(const float4*)(vp + d4 * 4);
                    acc[d4 * 4 + 0] += w * v4.x;
                    acc[d4 * 4 + 1] += w * v4.y;
                    acc[d4 * 4 + 2] += w * v4.z;
                    acc[d4 * 4 + 3] += w * v4.w;
                }
            }
        }
    }

    float inv = 1.f / l;
#pragma unroll
    for (int d4 = 0; d4 < 4; ++d4) {
        float4 o;
        o.x = acc[d4 * 4 + 0] * inv;
        o.y = acc[d4 * 4 + 1] * inv;
        o.z = acc[d4 * 4 + 2] * inv;
        o.w = acc[d4 * 4 + 3] * inv;
        *(float4*)&Ob[(size_t)qrow * CCH + h16 + d4 * 4] = o;
    }
}

// ---------------- Kernel 3: output projection + (y,x,t) transpose scatter ----------------
__launch_bounds__(256)
__global__ void out_proj_kernel(const float* __restrict__ A,
                                const float* __restrict__ Wo,
                                float* __restrict__ out) {
    __shared__ __align__(16) float xs[32][132];
    __shared__ __align__(16) float ws[64][132];
    const int tid = threadIdx.x;
    const int tx = tid & 31;
    const int ty = tid >> 5;
    const int r0 = blockIdx.x * 32;

    {
        const float4* src = (const float4*)(A + (size_t)r0 * CCH);
        for (int e = tid; e < 32 * 128 / 4; e += 256) {
            float4 v4 = src[e];
            int r = (e * 4) >> 7;
            int c = (e * 4) & 127;
            *(float4*)&xs[r][c] = v4;
        }
    }

    float acc[4][4];
#pragma unroll
    for (int i = 0; i < 4; ++i)
#pragma unroll
        for (int j = 0; j < 4; ++j) acc[i][j] = 0.f;

    for (int c0 = 0; c0 < 128; c0 += 64) {
        __syncthreads();
        const float4* wsrc = (const float4*)(Wo + (size_t)c0 * CCH);
        for (int e = tid; e < 64 * 128 / 4; e += 256) {
            float4 v4 = wsrc[e];
            int r = (e * 4) >> 7;
            int c = (e * 4) & 127;
            *(float4*)&ws[r][c] = v4;
        }
        __syncthreads();
#pragma unroll 8
        for (int cc = 0; cc < 64; ++cc) {
            float4 w4 = *(const float4*)&ws[cc][tx * 4];
#pragma unroll
            for (int i = 0; i < 4; ++i) {
                float xv = xs[ty * 4 + i][c0 + cc];
                acc[i][0] += xv * w4.x;
                acc[i][1] += xv * w4.y;
                acc[i][2] += xv * w4.z;
                acc[i][3] += xv * w4.w;
            }
        }
    }
#pragma unroll
    for (int i = 0; i < 4; ++i) {
        int row = r0 + ty * 4 + i;
        int t = row / (HH * WWD);
        int rem = row - t * (HH * WWD);
        int yy = rem / WWD;
        int xx = rem - yy * WWD;
        int k0 = tx * 4;
        float4 o;
        o.x = acc[i][0]; o.y = acc[i][1]; o.z = acc[i][2]; o.w = acc[i][3];
        size_t oidx = ((size_t)(yy * WWD + xx) * TT + t) * CCH + k0;
        *(float4*)&out[oidx] = o;
    }
}

extern "C" void kernel_launch(void* const* d_in, const int* in_sizes, int n_in,
                              void* d_out, int out_size, void* d_ws, size_t ws_size,
                              hipStream_t stream) {
    const float* x        = (const float*)d_in[0];
    const float* Wq       = (const float*)d_in[1];
    const float* Wk       = (const float*)d_in[2];
    const float* Wv       = (const float*)d_in[3];
    const float* Wo       = (const float*)d_in[4];
    const float* temp_emb = (const float*)d_in[5];
    const float* sp_emb   = (const float*)d_in[6];
    float* out = (float*)d_out;

    float* Qb = (float*)d_ws;
    float* Kb = Qb + (size_t)NROWS * CCH;
    float* Vb = Kb + (size_t)NROWS * CCH;

    qkv_kernel<<<NROWS / 32, 256, 0, stream>>>(x, Wq, Wk, Wv, temp_emb, sp_emb, Qb, Kb, Vb);
    attn_kernel<<<(HH / TY) * (WWD / TX), 384, 0, stream>>>(Qb, Kb, Vb, sp_emb, Qb);
    out_proj_kernel<<<NROWS / 32, 256, 0, stream>>>(Qb, Wo, out);
}